// Round 1
// 151.991 us; speedup vs baseline: 1.0485x; 1.0485x over previous
//
#include <hip/hip_runtime.h>
#include <math.h>

#define EMB 512
#define NH 8
#define HD 64
#define BB 2
#define SS 1024
#define ROWS (BB * SS) /* 2048 */

typedef __attribute__((ext_vector_type(8))) short bhalf8;
typedef __attribute__((ext_vector_type(4))) float f32x4;
typedef __attribute__((ext_vector_type(8))) unsigned short us8;
typedef unsigned short ushort_t;

typedef const __attribute__((address_space(1))) void gas_void;
typedef __attribute__((address_space(3))) void las_void;

__device__ __forceinline__ void gl2lds16(const void* g, void* l) {
  __builtin_amdgcn_global_load_lds((gas_void*)g, (las_void*)l, 16, 0, 0);
}

__device__ __forceinline__ unsigned short f2bf(float x) {
  unsigned u = __float_as_uint(x);
  u = (u + 0x7FFFu + ((u >> 16) & 1u)) >> 16;
  return (unsigned short)u;
}
__device__ __forceinline__ float bf2f(unsigned short v) {
  return __uint_as_float(((unsigned)v) << 16);
}
__device__ __forceinline__ float fast_tanh(float x) {
  x = fminf(15.f, fmaxf(-15.f, x));
  const float e = __expf(2.f * x);
  return (e - 1.f) / (e + 1.f);
}

// ============================================================
// prep: one-time f32->bf16 conversion of A-operands (f_emb, gpe),
// bf16 TRANSPOSED weights W^T[n][k] (so projpe can DMA-stage B tiles
// linearly), plus all workspace zeroing (Onum, lpart, Qcomb row 1023).
// Pure memory pass, ~25 MB total.
// Roles by blockIdx.x:
//   [0,128)   f_emb -> fembB (bf16)
//   [128,160) gpe   -> gpeB  (bf16)
//   [160,432) W transposes: 64x64 f32 tile -> bf16 [n][k]
//   [432,688) Onum zero (8 MB)
//   [688,692) lpart zero
//   [692]     Qcomb qp-half of row 1023 zero (no writer in projpe)
// ============================================================
__global__ __launch_bounds__(256) void prep_kernel(
    const float* __restrict__ f_emb, const float* __restrict__ gpe,
    const float* __restrict__ Wu, const float* __restrict__ Wq,
    const float* __restrict__ Wkv, const float* __restrict__ Wp,
    ushort_t* __restrict__ fembB, ushort_t* __restrict__ gpeB,
    ushort_t* __restrict__ WuT, ushort_t* __restrict__ WqT,
    ushort_t* __restrict__ WkvT, ushort_t* __restrict__ WpT,
    float* __restrict__ Onum, float* __restrict__ lpart,
    ushort_t* __restrict__ Qcomb) {
  __shared__ __align__(16) ushort_t sT[64 * 72];
  const int bid = blockIdx.x;
  const int tid = threadIdx.x;

  if (bid < 160) {  // contiguous f32 -> bf16
    const bool isF = bid < 128;
    const float* src = isF ? f_emb : gpe;
    ushort_t* dst = isF ? fembB : gpeB;
    const size_t base = (size_t)(isF ? bid : bid - 128) * 8192;
#pragma unroll
    for (int j = 0; j < 4; ++j) {
      const size_t off = base + ((size_t)j * 256 + tid) * 8;
      const float4 a = *(const float4*)&src[off];
      const float4 b = *(const float4*)&src[off + 4];
      us8 o;
      o[0] = f2bf(a.x); o[1] = f2bf(a.y); o[2] = f2bf(a.z); o[3] = f2bf(a.w);
      o[4] = f2bf(b.x); o[5] = f2bf(b.y); o[6] = f2bf(b.z); o[7] = f2bf(b.w);
      *(us8*)&dst[off] = o;
    }
  } else if (bid < 432) {  // 64x64 transpose tiles, f32 -> bf16
    int t = bid - 160;
    const float* W;
    ushort_t* WT;
    int Nw, Kd, k0, n0;
    if (t < 64) {
      W = Wu; WT = WuT; Nw = 512; Kd = 512;
      k0 = (t >> 3) * 64; n0 = (t & 7) * 64;
    } else if (t < 128) {
      t -= 64; W = Wq; WT = WqT; Nw = 512; Kd = 512;
      k0 = (t >> 3) * 64; n0 = (t & 7) * 64;
    } else if (t < 256) {
      t -= 128; W = Wkv; WT = WkvT; Nw = 1024; Kd = 512;
      k0 = (t >> 4) * 64; n0 = (t & 15) * 64;
    } else {
      t -= 256; W = Wp; WT = WpT; Nw = 512; Kd = 128;
      k0 = (t >> 3) * 64; n0 = (t & 7) * 64;
    }
    const int kk = tid >> 2, seg = tid & 3;
    const float* src = &W[(size_t)(k0 + kk) * Nw + n0 + seg * 16];
    float v[16];
    *(float4*)&v[0] = *(const float4*)&src[0];
    *(float4*)&v[4] = *(const float4*)&src[4];
    *(float4*)&v[8] = *(const float4*)&src[8];
    *(float4*)&v[12] = *(const float4*)&src[12];
#pragma unroll
    for (int i = 0; i < 16; ++i) sT[(seg * 16 + i) * 72 + kk] = f2bf(v[i]);
    __syncthreads();
#pragma unroll
    for (int p = 0; p < 2; ++p) {
      const int idx = p * 256 + tid;
      const int n = idx >> 3, c8 = (idx & 7) * 8;
      const us8 o = *(const us8*)&sT[n * 72 + c8];
      *(us8*)&WT[(size_t)(n0 + n) * Kd + k0 + c8] = o;
    }
  } else if (bid < 688) {  // Onum zero
    const float4 z = {0.f, 0.f, 0.f, 0.f};
    const size_t b0 = (size_t)(bid - 432) * 2048;
#pragma unroll
    for (int j = 0; j < 8; ++j) ((float4*)Onum)[b0 + j * 256 + tid] = z;
  } else if (bid < 692) {  // lpart zero
    const float4 z = {0.f, 0.f, 0.f, 0.f};
    const size_t b0 = (size_t)(bid - 688) * 2048;
#pragma unroll
    for (int j = 0; j < 8; ++j) ((float4*)lpart)[b0 + j * 256 + tid] = z;
  } else {  // Qcomb qp-half of row 1023
    const int t2 = tid >> 7, rem = tid & 127;
    const int h = rem >> 4, d4 = (rem & 15) * 4;
    *(ushort4*)&Qcomb[((size_t)t2 * ROWS + 1023) * 1024 + h * 128 + 64 + d4] =
        make_ushort4(0, 0, 0, 0);
  }
}

// ============================================================
// proj+pe GEMM: m97-style DMA pipeline. A (bf16) and W^T (bf16) tiles
// staged via global_load_lds (16B) into XOR-swizzled double-buffered
// LDS; ONE barrier per K-step; zero conversion VALU in main loop.
// Tile 128x64, identical MFMA order + epilogue to previous version
// (bit-identical numerics).
// ============================================================
__global__ __launch_bounds__(256, 3) void projpe_kernel(
    const ushort_t* __restrict__ fembB, const ushort_t* __restrict__ gpeB,
    const ushort_t* __restrict__ WuT, const ushort_t* __restrict__ WqT,
    const ushort_t* __restrict__ WkvT, const ushort_t* __restrict__ WpT,
    const float* __restrict__ Wu_b, const float* __restrict__ Wq_b,
    const float* __restrict__ Wkv_b, const float* __restrict__ Wp_b,
    const float* __restrict__ Buc, const float* __restrict__ Bup,
    const float* __restrict__ Bfc, const float* __restrict__ Bfp,
    ushort_t* __restrict__ Qcomb, ushort_t* __restrict__ Kcomb,
    ushort_t* __restrict__ vhT) {
  const int bx = blockIdx.x;
  const int mb = blockIdx.y * 128;
  const int tid = threadIdx.x;
  const int w = tid >> 6, lane = tid & 63;
  const int ln = lane & 15, quad = lane >> 4;
  const int wm = (w >> 1) * 64, wn = (w & 1) * 32;

  // bufA[p] = sMem + p*8192 (128x64), bufB[p] = sMem+16384 + p*4096 (64x64)
  __shared__ __align__(16) ushort_t sMem[24576];  // 48 KB

  const bool isPe = (bx >= 32);
  const int nb = isPe ? 0 : bx * 64;
  const int npbase = isPe ? (bx - 32) * 64 : 0;
  const ushort_t* Asrc = isPe ? gpeB : fembB;
  const int lda = isPe ? 128 : 512;
  const int trips = isPe ? 2 : 8;

  const ushort_t* Wt;
  int Kd, coff;
  if (isPe) { Wt = WpT; Kd = 128; coff = npbase; }
  else if (nb < 512) { Wt = WuT; Kd = 512; coff = nb; }
  else if (nb < 1024) { Wt = WqT; Kd = 512; coff = nb - 512; }
  else { Wt = WkvT; Kd = 512; coff = nb - 1024; }

  const int l3 = lane >> 3, c7 = lane & 7;
  const int swz = (c7 ^ l3) * 8;  // pre-swizzled source chunk (linear dest)

#define STAGE_PP(T_, P_)                                                     \
  {                                                                          \
    const int k1_ = (T_) * 64;                                               \
    ushort_t* dA_ = sMem + (P_) * 8192;                                      \
    ushort_t* dB_ = sMem + 16384 + (P_) * 4096;                              \
    _Pragma("unroll") for (int s_ = 0; s_ < 4; ++s_) {                       \
      const int q_ = w * 4 + s_;                                             \
      const int r_ = q_ * 8 + l3;                                            \
      gl2lds16(&Asrc[(size_t)(mb + r_) * lda + k1_ + swz], &dA_[q_ * 512]);  \
    }                                                                        \
    _Pragma("unroll") for (int s_ = 0; s_ < 2; ++s_) {                       \
      const int q_ = w * 2 + s_;                                             \
      const int r_ = q_ * 8 + l3;                                            \
      gl2lds16(&Wt[(size_t)(coff + r_) * Kd + k1_ + swz], &dB_[q_ * 512]);   \
    }                                                                        \
  }

  f32x4 acc[4][2];
#pragma unroll
  for (int rt = 0; rt < 4; ++rt)
#pragma unroll
    for (int ct = 0; ct < 2; ++ct) acc[rt][ct] = (f32x4){0.f, 0.f, 0.f, 0.f};

  STAGE_PP(0, 0);

  for (int t0 = 0; t0 < trips; ++t0) {
    __syncthreads();  // drains DMA for buffer (t0&1); syncs block
    if (t0 < trips - 1) STAGE_PP(t0 + 1, (t0 + 1) & 1);
    const ushort_t* bA = sMem + (t0 & 1) * 8192;
    const ushort_t* bB = sMem + 16384 + (t0 & 1) * 4096;
#pragma unroll
    for (int kc = 0; kc < 2; ++kc) {
      bhalf8 af[4], bfr[2];
#pragma unroll
      for (int rt = 0; rt < 4; ++rt) {
        const int row = wm + rt * 16 + ln;
        af[rt] = *(const bhalf8*)&bA[row * 64 +
                                     (((kc * 4 + quad) ^ (row & 7)) << 3)];
      }
#pragma unroll
      for (int ct = 0; ct < 2; ++ct) {
        const int row = wn + ct * 16 + ln;
        bfr[ct] = *(const bhalf8*)&bB[row * 64 +
                                      (((kc * 4 + quad) ^ (row & 7)) << 3)];
      }
#pragma unroll
      for (int rt = 0; rt < 4; ++rt)
#pragma unroll
        for (int ct = 0; ct < 2; ++ct)
          acc[rt][ct] = __builtin_amdgcn_mfma_f32_16x16x32_bf16(
              af[rt], bfr[ct], acc[rt][ct], 0, 0, 0);
    }
  }

  __syncthreads();
  ushort_t* sOut = sMem;

  if (!isPe && nb >= 1536) {
#pragma unroll
    for (int ct = 0; ct < 2; ++ct) {
      const int nl = wn + ct * 16 + ln;
      const float wb = Wkv_b[nb + nl - 1024];
#pragma unroll
      for (int rt = 0; rt < 4; ++rt)
#pragma unroll
        for (int r = 0; r < 4; ++r) {
          const int ml = wm + rt * 16 + quad * 4 + r;
          sOut[nl * 136 + ml] = f2bf(fast_tanh(acc[rt][ct][r] + wb));
        }
    }
    __syncthreads();
    const int b = mb >> 10, mo = mb & 1023;
#pragma unroll
    for (int i = 0; i < 4; ++i) {
      const int idx = tid + i * 256;
      const int nl = idx >> 4, m8 = (idx & 15) * 8;
      const us8 v = *(const us8*)&sOut[nl * 136 + m8];
      *(us8*)&vhT[((size_t)b * 512 + (nb - 1536) + nl) * 1024 + mo + m8] = v;
    }
  } else {
    const float* WB =
        isPe ? Wp_b : (nb < 512 ? Wu_b : (nb < 1024 ? Wq_b : Wkv_b));
    const int woff =
        isPe ? npbase : (nb < 512 ? nb : (nb < 1024 ? nb - 512 : nb - 1024));
    const bool rawDump = (!isPe && nb < 1024);
#pragma unroll
    for (int ct = 0; ct < 2; ++ct) {
      const int nl = wn + ct * 16 + ln;
      const float wb = WB[woff + nl];
#pragma unroll
      for (int rt = 0; rt < 4; ++rt)
#pragma unroll
        for (int r = 0; r < 4; ++r) {
          const int ml = wm + rt * 16 + quad * 4 + r;
          const float v = acc[rt][ct][r] + wb;
          sOut[ml * 72 + nl] = f2bf(rawDump ? v : fast_tanh(v));
        }
    }
    __syncthreads();
#pragma unroll
    for (int i = 0; i < 4; ++i) {
      const int idx = tid + i * 256;
      const int rr = idx >> 3, c8 = (idx & 7) * 8;
      const int m = mb + rr;
      const us8 v = *(const us8*)&sOut[rr * 72 + c8];
      if (isPe) {
        const int n = npbase + c8;
        const int h = n >> 6;
        *(us8*)&Kcomb[(size_t)m * 1024 + h * 128 + 64 + (n & 63)] = v;
      } else if (nb < 1024) {
        const int strm = nb >= 512 ? 1 : 0;
        const int n = (nb - strm * 512) + c8;
        const int h = n >> 6;
        const float* BC = strm ? Bfc : Buc;
        const float* BP = strm ? Bfp : Bup;
        float bcA[8], bpA[8];
        *(float4*)&bcA[0] = *(const float4*)&BC[n];
        *(float4*)&bcA[4] = *(const float4*)&BC[n + 4];
        *(float4*)&bpA[0] = *(const float4*)&BP[n];
        *(float4*)&bpA[4] = *(const float4*)&BP[n + 4];
        us8 oc, op;
#pragma unroll
        for (int jj = 0; jj < 8; ++jj) {
          const float vv = bf2f((unsigned short)v[jj]);
          oc[jj] = f2bf(fast_tanh(vv + bcA[jj]));
          op[jj] = f2bf(fast_tanh(vv + bpA[jj]));
        }
        *(us8*)&Qcomb[((size_t)strm * ROWS + m) * 1024 + h * 128 + (n & 63)] =
            oc;
        if (m != 0) {
          const int mp = (m < 1024) ? m - 1 : m;
          *(us8*)&Qcomb[((size_t)strm * ROWS + mp) * 1024 + h * 128 + 64 +
                        (n & 63)] = op;
        }
      } else {
        const int n = (nb - 1024) + c8;
        const int h = n >> 6;
        *(us8*)&Kcomb[(size_t)m * 1024 + h * 128 + (n & 63)] = v;
      }
    }
  }
}

// ============================================================
// attn: flash MFMA, static-max softmax. 512 uniform blocks, each
// handles 8-9 contiguous iters of the 4352-iter (combo x triangle)
// range. K/V staged via global_load_lds (16B DMA) into XOR-swizzled
// double-buffered LDS -> ONE barrier per iter, conflict-free reads.
// Partials accumulate into Onum/lpart via fp32 atomicAdd.
// ============================================================
__global__ __launch_bounds__(256, 2) void attn_kernel(
    const ushort_t* __restrict__ Qcomb, const ushort_t* __restrict__ Kcomb,
    const ushort_t* __restrict__ vhT, float* __restrict__ Onum,
    float* __restrict__ lpart) {
  const int bid = blockIdx.x;
  const int tid = threadIdx.x;
  const int w = tid >> 6, lane = tid & 63;
  const int ln = lane & 15, quad = lane >> 4;

  __shared__ __align__(16) ushort_t sK[2 * 64 * 128];  // 32 KB
  __shared__ __align__(16) ushort_t sV[2 * 64 * 64];   // 16 KB
  __shared__ __align__(16) ushort_t sP[64 * 72];       // 9 KB

  // global iter range
  const int G0 = (bid * 17) >> 1;
  const int G1 = ((bid + 1) * 17) >> 1;
  const int cnt = G1 - G0;

  int c = G0 / 136;
  int u = G0 - c * 136;
  int jt = (int)((sqrtf(8.f * u + 1.f) - 1.f) * 0.5f);
  while ((jt + 1) * (jt + 2) / 2 <= u) ++jt;
  while (jt * (jt + 1) / 2 > u) --jt;
  int kt = u - jt * (jt + 1) / 2;
  int t = c >> 4, b = (c >> 3) & 1, h = c & 7;

  // swizzled DMA staging of one K (64x128) + V (64x64) tile
  const int l4 = lane >> 4, p15 = lane & 15;
  const int l3 = lane >> 3, l7 = lane & 7;
#define STAGE_KV(B_, H_, KT_, BUF_)                                          \
  {                                                                          \
    const size_t kb_ = ((size_t)(B_)*SS + (KT_)*64) * 1024 + (H_)*128;       \
    ushort_t* bk_ = sK + (BUF_)*8192;                                        \
    _Pragma("unroll") for (int s_ = 0; s_ < 4; ++s_) {                       \
      const int q_ = w * 4 + s_;                                             \
      const int r_ = q_ * 4 + l4;                                            \
      const int gl_ = p15 ^ (r_ & 7);                                        \
      gl2lds16(&Kcomb[kb_ + (size_t)r_ * 1024 + gl_ * 8], &bk_[q_ * 512]);   \
    }                                                                        \
    const size_t vb_ = ((size_t)(B_)*512 + (H_)*64) * 1024 + (KT_)*64;       \
    ushort_t* bv_ = sV + (BUF_)*4096;                                        \
    _Pragma("unroll") for (int s_ = 0; s_ < 2; ++s_) {                       \
      const int q_ = w * 2 + s_;                                             \
      const int r_ = q_ * 8 + l3;                                            \
      const int gl_ = l7 ^ (r_ & 7);                                         \
      gl2lds16(&vhT[vb_ + (size_t)r_ * 1024 + gl_ * 8], &bv_[q_ * 512]);     \
    }                                                                        \
  }

  // Q fragments for (t,b,h,jt)
  bhalf8 aq[4];
#define LOAD_AQ(T_, B_, H_, JT_)                                             \
  {                                                                          \
    const size_t qb_ =                                                       \
        ((size_t)(T_)*ROWS + (B_)*SS + (JT_)*64 + w * 16 + ln) * 1024 +      \
        (H_)*128 + quad * 8;                                                 \
    _Pragma("unroll") for (int kc_ = 0; kc_ < 4; ++kc_) aq[kc_] =            \
        *(const bhalf8*)&Qcomb[qb_ + kc_ * 32];                              \
  }

  STAGE_KV(b, h, kt, 0);
  LOAD_AQ(t, b, h, jt);

  f32x4 oacc[4];
#pragma unroll
  for (int ct = 0; ct < 4; ++ct) oacc[ct] = (f32x4){0.f, 0.f, 0.f, 0.f};
  float lsum[4] = {0.f, 0.f, 0.f, 0.f};

  for (int it = 0; it < cnt; ++it) {
    __syncthreads();  // drains DMA for buffer (it&1); syncs block
    const ushort_t* bK = sK + (it & 1) * 8192;
    const ushort_t* bV = sV + (it & 1) * 4096;

    // next coords + DMA prefetch into other buffer
    int c2 = c, jt2 = jt, kt2 = kt + 1;
    if (kt2 > jt) {
      jt2 = jt + 1; kt2 = 0;
      if (jt2 > 15) { c2 = c + 1; jt2 = 0; }
    }
    if (it < cnt - 1) {
      const int b2 = (c2 >> 3) & 1, h2 = c2 & 7;
      STAGE_KV(b2, h2, kt2, ((it + 1) & 1));
    }

    // S = Q2 @ K2^T (swizzled reads)
    f32x4 sacc[4];
#pragma unroll
    for (int ct = 0; ct < 4; ++ct) {
      sacc[ct] = (f32x4){0.f, 0.f, 0.f, 0.f};
#pragma unroll
      for (int kc = 0; kc < 4; ++kc) {
        const bhalf8 bk = *(const bhalf8*)&bK[(ct * 16 + ln) * 128 +
                                             (((kc * 4 + quad) ^ l7) << 3)];
        sacc[ct] = __builtin_amdgcn_mfma_f32_16x16x32_bf16(aq[kc], bk,
                                                           sacc[ct], 0, 0, 0);
      }
    }

    const bool diag = (kt == jt);
#pragma unroll
    for (int ct = 0; ct < 4; ++ct)
#pragma unroll
      for (int r = 0; r < 4; ++r) {
        float p;
        if (diag && (ct * 16 + ln > w * 16 + quad * 4 + r))
          p = 0.f;
        else
          p = __expf(sacc[ct][r] * 0.125f - 16.f);
        sacc[ct][r] = p;
        lsum[r] += p;
      }

#pragma unroll
    for (int ct = 0; ct < 4; ++ct)
#pragma unroll
      for (int r = 0; r < 4; ++r)
        sP[(w * 16 + quad * 4 + r) * 72 + ct * 16 + ln] =
            (ushort_t)(__float_as_uint(sacc[ct][r]) >> 16);

#pragma unroll
    for (int kc = 0; kc < 2; ++kc) {
      const bhalf8 ap =
          *(const bhalf8*)&sP[(w * 16 + ln) * 72 + kc * 32 + quad * 8];
#pragma unroll
      for (int ct = 0; ct < 4; ++ct) {
        const bhalf8 bv = *(const bhalf8*)&bV[(ct * 16 + ln) * 64 +
                                             (((kc * 4 + quad) ^ l7) << 3)];
        oacc[ct] = __builtin_amdgcn_mfma_f32_16x16x32_bf16(ap, bv, oacc[ct],
                                                           0, 0, 0);
      }
    }

    // flush on row/combo change or end
    const bool rowEnd = (it == cnt - 1) || (jt2 != jt) || (c2 != c);
    if (rowEnd) {
#pragma unroll
      for (int r = 0; r < 4; ++r) {
        float s = lsum[r];
        s += __shfl_xor(s, 1);
        s += __shfl_xor(s, 2);
        s += __shfl_xor(s, 4);
        s += __shfl_xor(s, 8);
        const int j = jt * 64 + w * 16 + quad * 4 + r;
        if (ln == 0)
          atomicAdd(&lpart[((((t * 2 + b) << 10) + j) << 3) + h], s);
        const size_t orow = (((size_t)t * ROWS + b * SS + j) << 9) + h * 64;
#pragma unroll
        for (int ct = 0; ct < 4; ++ct)
          atomicAdd(&Onum[orow + ct * 16 + ln], oacc[ct][r]);
        lsum[r] = 0.f;
      }
#pragma unroll
      for (int ct = 0; ct < 4; ++ct) oacc[ct] = (f32x4){0.f, 0.f, 0.f, 0.f};
      if (it < cnt - 1) {
        const int t2 = c2 >> 4, b2 = (c2 >> 3) & 1, h2 = c2 & 7;
        LOAD_AQ(t2, b2, h2, jt2);
      }
    }
    c = c2; jt = jt2; kt = kt2;
    t = c >> 4; b = (c >> 3) & 1; h = c & 7;
  }
}

// ============================================================
// ln: y = resid + Onum/lpart, layernorm. One wave per row.
// ============================================================
__global__ __launch_bounds__(256) void ln_kernel(
    const float* __restrict__ u_emb, const float* __restrict__ f_emb,
    const float* __restrict__ Onum, const float* __restrict__ lpart,
    float* __restrict__ out) {
  const int rid = blockIdx.x * 4 + (threadIdx.x >> 6);
  const int lane = threadIdx.x & 63;
  const int t = rid >> 11, row = rid & 2047;
  const int b = row >> 10, j = row & 1023;
  const float* resid = t ? f_emb : u_emb;
  const size_t base = (size_t)row * 512;
  const size_t obase = ((size_t)t * ROWS + row) * 512;
  const int o = lane * 8;
  const int h = lane >> 3;
  const float inv = 1.f / lpart[((((t * 2 + b) << 10) + j) << 3) + h];

  const float4 n0 = *(const float4*)&Onum[obase + o];
  const float4 n1 = *(const float4*)&Onum[obase + o + 4];
  const float4 r0 = *(const float4*)&resid[base + o];
  const float4 r1 = *(const float4*)&resid[base + o + 4];
  float y[8];
  y[0] = r0.x + n0.x * inv; y[1] = r0.y + n0.y * inv;
  y[2] = r0.z + n0.z * inv; y[3] = r0.w + n0.w * inv;
  y[4] = r1.x + n1.x * inv; y[5] = r1.y + n1.y * inv;
  y[6] = r1.z + n1.z * inv; y[7] = r1.w + n1.w * inv;

  float s = 0.f, q = 0.f;
#pragma unroll
  for (int i = 0; i < 8; ++i) {
    s += y[i];
    q += y[i] * y[i];
  }
#pragma unroll
  for (int off = 1; off < 64; off <<= 1) {
    s += __shfl_xor(s, off);
    q += __shfl_xor(q, off);
  }
  const float mean = s * (1.f / 512.f);
  const float var = q * (1.f / 512.f) - mean * mean;
  const float rstd = rsqrtf(var + 1e-5f);

  float4 o0, o1;
  o0.x = (y[0] - mean) * rstd; o0.y = (y[1] - mean) * rstd;
  o0.z = (y[2] - mean) * rstd; o0.w = (y[3] - mean) * rstd;
  o1.x = (y[4] - mean) * rstd; o1.y = (y[5] - mean) * rstd;
  o1.z = (y[6] - mean) * rstd; o1.w = (y[7] - mean) * rstd;
  *(float4*)&out[obase + o] = o0;
  *(float4*)&out[obase + o + 4] = o1;
}

// ============================================================
extern "C" void kernel_launch(void* const* d_in, const int* in_sizes, int n_in,
                              void* d_out, int out_size, void* d_ws,
                              size_t ws_size, hipStream_t stream) {
  (void)in_sizes; (void)n_in; (void)out_size; (void)ws_size;
  const float* u_emb = (const float*)d_in[0];
  const float* f_emb = (const float*)d_in[1];
  const float* gpe = (const float*)d_in[2];
  const float* Wq_w = (const float*)d_in[5];
  const float* Wq_b = (const float*)d_in[6];
  const float* Wkv_w = (const float*)d_in[7];
  const float* Wkv_b = (const float*)d_in[8];
  const float* Wp_w = (const float*)d_in[9];
  const float* Wp_b = (const float*)d_in[10];
  const float* Wu_w = (const float*)d_in[11];
  const float* Wu_b = (const float*)d_in[12];
  const float* Bfc = (const float*)d_in[13];
  const float* Bfp = (const float*)d_in[14];
  const float* Buc = (const float*)d_in[15];
  const float* Bup = (const float*)d_in[16];
  float* out = (float*)d_out;

  ushort_t* ws = (ushort_t*)d_ws;
  const size_t SZ = (size_t)ROWS * EMB;       // 1048576
  ushort_t* Qcomb = ws;                       // 4*SZ
  ushort_t* Kcomb = ws + 4 * SZ;              // 2*SZ
  ushort_t* vhT = ws + 6 * SZ;                // SZ
  float* Onum = (float*)(ws + 7 * SZ);        // 2M floats (8 MB)
  float* lpart = (float*)(ws + 11 * SZ);      // 32768 floats
  ushort_t* fembB = ws + 12 * SZ;             // SZ        (2048x512 bf16)
  ushort_t* gpeB = ws + 13 * SZ;              // SZ/4      (2048x128 bf16)
  ushort_t* WuT = ws + 13 * SZ + SZ / 4;      // SZ/4      (512x512 [n][k])
  ushort_t* WqT = ws + 13 * SZ + SZ / 2;      // SZ/4
  ushort_t* WkvT = ws + 13 * SZ + 3 * (SZ / 4);  // SZ/2   (1024x512 [n][k])
  ushort_t* WpT = ws + 13 * SZ + 5 * (SZ / 4);   // SZ/16  (512x128 [n][k])

  dim3 blk(256);
  hipLaunchKernelGGL(prep_kernel, dim3(693), blk, 0, stream, f_emb, gpe, Wu_w,
                     Wq_w, Wkv_w, Wp_w, fembB, gpeB, WuT, WqT, WkvT, WpT, Onum,
                     lpart, Qcomb);
  hipLaunchKernelGGL(projpe_kernel, dim3(40, 16), blk, 0, stream, fembB, gpeB,
                     WuT, WqT, WkvT, WpT, Wu_b, Wq_b, Wkv_b, Wp_b, Buc, Bup,
                     Bfc, Bfp, Qcomb, Kcomb, vhT);
  hipLaunchKernelGGL(attn_kernel, dim3(512), blk, 0, stream, Qcomb, Kcomb, vhT,
                     Onum, lpart);
  hipLaunchKernelGGL(ln_kernel, dim3(1024), blk, 0, stream, u_emb, f_emb, Onum,
                     lpart, out);
}

// Round 2
// 148.174 us; speedup vs baseline: 1.0755x; 1.0258x over previous
//
#include <hip/hip_runtime.h>
#include <math.h>

#define EMB 512
#define NH 8
#define HD 64
#define BB 2
#define SS 1024
#define ROWS (BB * SS) /* 2048 */

typedef __attribute__((ext_vector_type(8))) short bhalf8;
typedef __attribute__((ext_vector_type(4))) float f32x4;
typedef __attribute__((ext_vector_type(8))) unsigned short us8;
typedef unsigned short ushort_t;

typedef const __attribute__((address_space(1))) void gas_void;
typedef __attribute__((address_space(3))) void las_void;

__device__ __forceinline__ void gl2lds16(const void* g, void* l) {
  __builtin_amdgcn_global_load_lds((gas_void*)g, (las_void*)l, 16, 0, 0);
}

__device__ __forceinline__ unsigned short f2bf(float x) {
  unsigned u = __float_as_uint(x);
  u = (u + 0x7FFFu + ((u >> 16) & 1u)) >> 16;
  return (unsigned short)u;
}
__device__ __forceinline__ float bf2f(unsigned short v) {
  return __uint_as_float(((unsigned)v) << 16);
}
__device__ __forceinline__ float fast_tanh(float x) {
  x = fminf(15.f, fmaxf(-15.f, x));
  const float e = __expf(2.f * x);
  return (e - 1.f) / (e + 1.f);
}

// ============================================================
// prep: one-time f32->bf16 conversion of A-operands (f_emb, gpe),
// bf16 TRANSPOSED weights W^T[n][k], plus Qcomb row-1023 zero.
// (Onum/lpart zeroing REMOVED - attn no longer accumulates atomically.)
// Roles by blockIdx.x:
//   [0,128)   f_emb -> fembB (bf16)
//   [128,160) gpe   -> gpeB  (bf16)
//   [160,432) W transposes: 64x64 f32 tile -> bf16 [n][k]
//   [432]     Qcomb qp-half of row 1023 zero (no writer in projpe)
// ============================================================
__global__ __launch_bounds__(256) void prep_kernel(
    const float* __restrict__ f_emb, const float* __restrict__ gpe,
    const float* __restrict__ Wu, const float* __restrict__ Wq,
    const float* __restrict__ Wkv, const float* __restrict__ Wp,
    ushort_t* __restrict__ fembB, ushort_t* __restrict__ gpeB,
    ushort_t* __restrict__ WuT, ushort_t* __restrict__ WqT,
    ushort_t* __restrict__ WkvT, ushort_t* __restrict__ WpT,
    ushort_t* __restrict__ Qcomb) {
  __shared__ __align__(16) ushort_t sT[64 * 72];
  const int bid = blockIdx.x;
  const int tid = threadIdx.x;

  if (bid < 160) {  // contiguous f32 -> bf16
    const bool isF = bid < 128;
    const float* src = isF ? f_emb : gpe;
    ushort_t* dst = isF ? fembB : gpeB;
    const size_t base = (size_t)(isF ? bid : bid - 128) * 8192;
#pragma unroll
    for (int j = 0; j < 4; ++j) {
      const size_t off = base + ((size_t)j * 256 + tid) * 8;
      const float4 a = *(const float4*)&src[off];
      const float4 b = *(const float4*)&src[off + 4];
      us8 o;
      o[0] = f2bf(a.x); o[1] = f2bf(a.y); o[2] = f2bf(a.z); o[3] = f2bf(a.w);
      o[4] = f2bf(b.x); o[5] = f2bf(b.y); o[6] = f2bf(b.z); o[7] = f2bf(b.w);
      *(us8*)&dst[off] = o;
    }
  } else if (bid < 432) {  // 64x64 transpose tiles, f32 -> bf16
    int t = bid - 160;
    const float* W;
    ushort_t* WT;
    int Nw, Kd, k0, n0;
    if (t < 64) {
      W = Wu; WT = WuT; Nw = 512; Kd = 512;
      k0 = (t >> 3) * 64; n0 = (t & 7) * 64;
    } else if (t < 128) {
      t -= 64; W = Wq; WT = WqT; Nw = 512; Kd = 512;
      k0 = (t >> 3) * 64; n0 = (t & 7) * 64;
    } else if (t < 256) {
      t -= 128; W = Wkv; WT = WkvT; Nw = 1024; Kd = 512;
      k0 = (t >> 4) * 64; n0 = (t & 15) * 64;
    } else {
      t -= 256; W = Wp; WT = WpT; Nw = 512; Kd = 128;
      k0 = (t >> 3) * 64; n0 = (t & 7) * 64;
    }
    const int kk = tid >> 2, seg = tid & 3;
    const float* src = &W[(size_t)(k0 + kk) * Nw + n0 + seg * 16];
    float v[16];
    *(float4*)&v[0] = *(const float4*)&src[0];
    *(float4*)&v[4] = *(const float4*)&src[4];
    *(float4*)&v[8] = *(const float4*)&src[8];
    *(float4*)&v[12] = *(const float4*)&src[12];
#pragma unroll
    for (int i = 0; i < 16; ++i) sT[(seg * 16 + i) * 72 + kk] = f2bf(v[i]);
    __syncthreads();
#pragma unroll
    for (int p = 0; p < 2; ++p) {
      const int idx = p * 256 + tid;
      const int n = idx >> 3, c8 = (idx & 7) * 8;
      const us8 o = *(const us8*)&sT[n * 72 + c8];
      *(us8*)&WT[(size_t)(n0 + n) * Kd + k0 + c8] = o;
    }
  } else {  // Qcomb qp-half of row 1023
    const int t2 = tid >> 7, rem = tid & 127;
    const int h = rem >> 4, d4 = (rem & 15) * 4;
    *(ushort4*)&Qcomb[((size_t)t2 * ROWS + 1023) * 1024 + h * 128 + 64 + d4] =
        make_ushort4(0, 0, 0, 0);
  }
}

// ============================================================
// proj+pe GEMM: m97-style DMA pipeline (unchanged from R1).
// ============================================================
__global__ __launch_bounds__(256, 3) void projpe_kernel(
    const ushort_t* __restrict__ fembB, const ushort_t* __restrict__ gpeB,
    const ushort_t* __restrict__ WuT, const ushort_t* __restrict__ WqT,
    const ushort_t* __restrict__ WkvT, const ushort_t* __restrict__ WpT,
    const float* __restrict__ Wu_b, const float* __restrict__ Wq_b,
    const float* __restrict__ Wkv_b, const float* __restrict__ Wp_b,
    const float* __restrict__ Buc, const float* __restrict__ Bup,
    const float* __restrict__ Bfc, const float* __restrict__ Bfp,
    ushort_t* __restrict__ Qcomb, ushort_t* __restrict__ Kcomb,
    ushort_t* __restrict__ vhT) {
  const int bx = blockIdx.x;
  const int mb = blockIdx.y * 128;
  const int tid = threadIdx.x;
  const int w = tid >> 6, lane = tid & 63;
  const int ln = lane & 15, quad = lane >> 4;
  const int wm = (w >> 1) * 64, wn = (w & 1) * 32;

  __shared__ __align__(16) ushort_t sMem[24576];  // 48 KB

  const bool isPe = (bx >= 32);
  const int nb = isPe ? 0 : bx * 64;
  const int npbase = isPe ? (bx - 32) * 64 : 0;
  const ushort_t* Asrc = isPe ? gpeB : fembB;
  const int lda = isPe ? 128 : 512;
  const int trips = isPe ? 2 : 8;

  const ushort_t* Wt;
  int Kd, coff;
  if (isPe) { Wt = WpT; Kd = 128; coff = npbase; }
  else if (nb < 512) { Wt = WuT; Kd = 512; coff = nb; }
  else if (nb < 1024) { Wt = WqT; Kd = 512; coff = nb - 512; }
  else { Wt = WkvT; Kd = 512; coff = nb - 1024; }

  const int l3 = lane >> 3, c7 = lane & 7;
  const int swz = (c7 ^ l3) * 8;  // pre-swizzled source chunk (linear dest)

#define STAGE_PP(T_, P_)                                                     \
  {                                                                          \
    const int k1_ = (T_) * 64;                                               \
    ushort_t* dA_ = sMem + (P_) * 8192;                                      \
    ushort_t* dB_ = sMem + 16384 + (P_) * 4096;                              \
    _Pragma("unroll") for (int s_ = 0; s_ < 4; ++s_) {                       \
      const int q_ = w * 4 + s_;                                             \
      const int r_ = q_ * 8 + l3;                                            \
      gl2lds16(&Asrc[(size_t)(mb + r_) * lda + k1_ + swz], &dA_[q_ * 512]);  \
    }                                                                        \
    _Pragma("unroll") for (int s_ = 0; s_ < 2; ++s_) {                       \
      const int q_ = w * 2 + s_;                                             \
      const int r_ = q_ * 8 + l3;                                            \
      gl2lds16(&Wt[(size_t)(coff + r_) * Kd + k1_ + swz], &dB_[q_ * 512]);   \
    }                                                                        \
  }

  f32x4 acc[4][2];
#pragma unroll
  for (int rt = 0; rt < 4; ++rt)
#pragma unroll
    for (int ct = 0; ct < 2; ++ct) acc[rt][ct] = (f32x4){0.f, 0.f, 0.f, 0.f};

  STAGE_PP(0, 0);

  for (int t0 = 0; t0 < trips; ++t0) {
    __syncthreads();
    if (t0 < trips - 1) STAGE_PP(t0 + 1, (t0 + 1) & 1);
    const ushort_t* bA = sMem + (t0 & 1) * 8192;
    const ushort_t* bB = sMem + 16384 + (t0 & 1) * 4096;
#pragma unroll
    for (int kc = 0; kc < 2; ++kc) {
      bhalf8 af[4], bfr[2];
#pragma unroll
      for (int rt = 0; rt < 4; ++rt) {
        const int row = wm + rt * 16 + ln;
        af[rt] = *(const bhalf8*)&bA[row * 64 +
                                     (((kc * 4 + quad) ^ (row & 7)) << 3)];
      }
#pragma unroll
      for (int ct = 0; ct < 2; ++ct) {
        const int row = wn + ct * 16 + ln;
        bfr[ct] = *(const bhalf8*)&bB[row * 64 +
                                      (((kc * 4 + quad) ^ (row & 7)) << 3)];
      }
#pragma unroll
      for (int rt = 0; rt < 4; ++rt)
#pragma unroll
        for (int ct = 0; ct < 2; ++ct)
          acc[rt][ct] = __builtin_amdgcn_mfma_f32_16x16x32_bf16(
              af[rt], bfr[ct], acc[rt][ct], 0, 0, 0);
    }
  }

  __syncthreads();
  ushort_t* sOut = sMem;

  if (!isPe && nb >= 1536) {
#pragma unroll
    for (int ct = 0; ct < 2; ++ct) {
      const int nl = wn + ct * 16 + ln;
      const float wb = Wkv_b[nb + nl - 1024];
#pragma unroll
      for (int rt = 0; rt < 4; ++rt)
#pragma unroll
        for (int r = 0; r < 4; ++r) {
          const int ml = wm + rt * 16 + quad * 4 + r;
          sOut[nl * 136 + ml] = f2bf(fast_tanh(acc[rt][ct][r] + wb));
        }
    }
    __syncthreads();
    const int b = mb >> 10, mo = mb & 1023;
#pragma unroll
    for (int i = 0; i < 4; ++i) {
      const int idx = tid + i * 256;
      const int nl = idx >> 4, m8 = (idx & 15) * 8;
      const us8 v = *(const us8*)&sOut[nl * 136 + m8];
      *(us8*)&vhT[((size_t)b * 512 + (nb - 1536) + nl) * 1024 + mo + m8] = v;
    }
  } else {
    const float* WB =
        isPe ? Wp_b : (nb < 512 ? Wu_b : (nb < 1024 ? Wq_b : Wkv_b));
    const int woff =
        isPe ? npbase : (nb < 512 ? nb : (nb < 1024 ? nb - 512 : nb - 1024));
    const bool rawDump = (!isPe && nb < 1024);
#pragma unroll
    for (int ct = 0; ct < 2; ++ct) {
      const int nl = wn + ct * 16 + ln;
      const float wb = WB[woff + nl];
#pragma unroll
      for (int rt = 0; rt < 4; ++rt)
#pragma unroll
        for (int r = 0; r < 4; ++r) {
          const int ml = wm + rt * 16 + quad * 4 + r;
          const float v = acc[rt][ct][r] + wb;
          sOut[ml * 72 + nl] = f2bf(rawDump ? v : fast_tanh(v));
        }
    }
    __syncthreads();
#pragma unroll
    for (int i = 0; i < 4; ++i) {
      const int idx = tid + i * 256;
      const int rr = idx >> 3, c8 = (idx & 7) * 8;
      const int m = mb + rr;
      const us8 v = *(const us8*)&sOut[rr * 72 + c8];
      if (isPe) {
        const int n = npbase + c8;
        const int h = n >> 6;
        *(us8*)&Kcomb[(size_t)m * 1024 + h * 128 + 64 + (n & 63)] = v;
      } else if (nb < 1024) {
        const int strm = nb >= 512 ? 1 : 0;
        const int n = (nb - strm * 512) + c8;
        const int h = n >> 6;
        const float* BC = strm ? Bfc : Buc;
        const float* BP = strm ? Bfp : Bup;
        float bcA[8], bpA[8];
        *(float4*)&bcA[0] = *(const float4*)&BC[n];
        *(float4*)&bcA[4] = *(const float4*)&BC[n + 4];
        *(float4*)&bpA[0] = *(const float4*)&BP[n];
        *(float4*)&bpA[4] = *(const float4*)&BP[n + 4];
        us8 oc, op;
#pragma unroll
        for (int jj = 0; jj < 8; ++jj) {
          const float vv = bf2f((unsigned short)v[jj]);
          oc[jj] = f2bf(fast_tanh(vv + bcA[jj]));
          op[jj] = f2bf(fast_tanh(vv + bpA[jj]));
        }
        *(us8*)&Qcomb[((size_t)strm * ROWS + m) * 1024 + h * 128 + (n & 63)] =
            oc;
        if (m != 0) {
          const int mp = (m < 1024) ? m - 1 : m;
          *(us8*)&Qcomb[((size_t)strm * ROWS + mp) * 1024 + h * 128 + 64 +
                        (n & 63)] = op;
        }
      } else {
        const int n = (nb - 1024) + c8;
        const int h = n >> 6;
        *(us8*)&Kcomb[(size_t)m * 1024 + h * 128 + (n & 63)] = v;
      }
    }
  }
}

// ============================================================
// attn: flash MFMA, static-max softmax, ZERO ATOMICS.
// 256 blocks x 512 threads (8 warps). Each block owns a balanced
// jt-pair (jt, 15-jt) for one (t,b,h) combo: exactly 17 tile-iters.
// 8 warps split the 64x64 tile: 4 row-tiles x 2 col-halves.
// Per iter: full sync (drains K/V DMA) -> QK MFMA -> exp -> sP write
// -> raw lgkmcnt(0)+s_barrier (DMA prefetch stays in flight!) -> PV.
// Rows flushed once: normalized O written directly (no Onum RMW).
// ============================================================
__global__ __launch_bounds__(512, 2) void attn_kernel(
    const ushort_t* __restrict__ Qcomb, const ushort_t* __restrict__ Kcomb,
    const ushort_t* __restrict__ vhT, float* __restrict__ Ofin) {
  const int bid = blockIdx.x;
  const int tid = threadIdx.x;
  const int w = tid >> 6, lane = tid & 63;
  const int ln = lane & 15, quad = lane >> 4;
  const int wr = w >> 1, wc = w & 1;
  const int l4 = lane >> 4, p15 = lane & 15;
  const int l3 = lane >> 3, l7 = lane & 7;

  __shared__ __align__(16) ushort_t sK[2 * 8192];  // 32 KB
  __shared__ __align__(16) ushort_t sV[2 * 4096];  // 16 KB
  __shared__ __align__(16) ushort_t sP[64 * 72];   // 9 KB
  __shared__ float lsf[2][64];                     // 0.5 KB

  const int c = bid >> 3, pi = bid & 7;
  const int jA = 15 - pi, jB = pi;  // jA >= 8 > jB, jA+jB = 15
  const int t = c >> 4, b = (c >> 3) & 1, h = c & 7;

#define STAGE_KV(KT_, BUF_)                                                   \
  {                                                                           \
    const size_t kb_ = ((size_t)b * SS + (KT_)*64) * 1024 + h * 128;          \
    ushort_t* bk_ = sK + (BUF_)*8192;                                         \
    _Pragma("unroll") for (int s_ = 0; s_ < 2; ++s_) {                        \
      const int q_ = w * 2 + s_;                                              \
      const int r_ = q_ * 4 + l4;                                             \
      const int gl_ = p15 ^ (r_ & 7);                                         \
      gl2lds16(&Kcomb[kb_ + (size_t)r_ * 1024 + gl_ * 8], &bk_[q_ * 512]);    \
    }                                                                         \
    const size_t vb_ = ((size_t)b * 512 + h * 64) * 1024 + (KT_)*64;          \
    ushort_t* bv_ = sV + (BUF_)*4096;                                         \
    {                                                                         \
      const int r_ = w * 8 + l3;                                              \
      const int gl_ = l7 ^ (r_ & 7);                                          \
      gl2lds16(&vhT[vb_ + (size_t)r_ * 1024 + gl_ * 8], &bv_[w * 512]);       \
    }                                                                         \
  }

  bhalf8 aq[4];
#define LOAD_AQ(JT_)                                                          \
  {                                                                           \
    const size_t qb_ =                                                        \
        ((size_t)t * ROWS + b * SS + (JT_)*64 + wr * 16 + ln) * 1024 +        \
        h * 128 + quad * 8;                                                   \
    _Pragma("unroll") for (int kc_ = 0; kc_ < 4; ++kc_) aq[kc_] =             \
        *(const bhalf8*)&Qcomb[qb_ + kc_ * 32];                               \
  }

  STAGE_KV(0, 0);
  LOAD_AQ(jA);

  f32x4 oacc[2];
  oacc[0] = (f32x4){0.f, 0.f, 0.f, 0.f};
  oacc[1] = (f32x4){0.f, 0.f, 0.f, 0.f};
  float lsum[4] = {0.f, 0.f, 0.f, 0.f};

  int jt = jA, kt = 0;
  for (int it = 0; it < 17; ++it) {
    __syncthreads();  // drains this buffer's DMA; syncs block
    const ushort_t* bK = sK + (it & 1) * 8192;
    const ushort_t* bV = sV + (it & 1) * 4096;

    // next coords + DMA prefetch into other buffer (full-iter window)
    int jt2 = jt, kt2 = kt + 1;
    if (kt2 > jt) { jt2 = jB; kt2 = 0; }
    if (it < 16) STAGE_KV(kt2, ((it + 1) & 1));

    // S = Q @ K^T : this warp's 16 rows x 32 cols (col-half wc)
    f32x4 sacc[2];
#pragma unroll
    for (int ct = 0; ct < 2; ++ct) {
      sacc[ct] = (f32x4){0.f, 0.f, 0.f, 0.f};
#pragma unroll
      for (int kc = 0; kc < 4; ++kc) {
        const bhalf8 bk =
            *(const bhalf8*)&bK[(wc * 32 + ct * 16 + ln) * 128 +
                                (((kc * 4 + quad) ^ l7) << 3)];
        sacc[ct] = __builtin_amdgcn_mfma_f32_16x16x32_bf16(aq[kc], bk,
                                                           sacc[ct], 0, 0, 0);
      }
    }

    const bool diag = (kt == jt);
#pragma unroll
    for (int ct = 0; ct < 2; ++ct)
#pragma unroll
      for (int r = 0; r < 4; ++r) {
        float p;
        if (diag && (wc * 32 + ct * 16 + ln > wr * 16 + quad * 4 + r))
          p = 0.f;
        else
          p = __expf(sacc[ct][r] * 0.125f - 16.f);
        sacc[ct][r] = p;
        lsum[r] += p;
      }

#pragma unroll
    for (int ct = 0; ct < 2; ++ct)
#pragma unroll
      for (int r = 0; r < 4; ++r)
        sP[(wr * 16 + quad * 4 + r) * 72 + wc * 32 + ct * 16 + ln] =
            (ushort_t)(__float_as_uint(sacc[ct][r]) >> 16);

    // LDS-only barrier: sP visible block-wide; K/V DMA stays in flight.
    asm volatile("s_waitcnt lgkmcnt(0)" ::: "memory");
    __builtin_amdgcn_s_barrier();
    __builtin_amdgcn_sched_barrier(0);

    // O += P @ V : this warp's 16 rows x 32 d-cols (d-half wc)
#pragma unroll
    for (int kc = 0; kc < 2; ++kc) {
      const bhalf8 ap =
          *(const bhalf8*)&sP[(wr * 16 + ln) * 72 + kc * 32 + quad * 8];
#pragma unroll
      for (int ct = 0; ct < 2; ++ct) {
        const bhalf8 bv =
            *(const bhalf8*)&bV[(wc * 32 + ct * 16 + ln) * 64 +
                                (((kc * 4 + quad) ^ l7) << 3)];
        oacc[ct] = __builtin_amdgcn_mfma_f32_16x16x32_bf16(ap, bv, oacc[ct],
                                                           0, 0, 0);
      }
    }

    // flush once per row-block (kt == jt): normalize + direct store
    if (kt == jt) {
#pragma unroll
      for (int r = 0; r < 4; ++r) {
        float s = lsum[r];
        s += __shfl_xor(s, 1);
        s += __shfl_xor(s, 2);
        s += __shfl_xor(s, 4);
        s += __shfl_xor(s, 8);
        if (ln == 0) lsf[wc][wr * 16 + quad * 4 + r] = s;
      }
      __syncthreads();
#pragma unroll
      for (int r = 0; r < 4; ++r) {
        const int rl = wr * 16 + quad * 4 + r;
        const float rinv = 1.f / (lsf[0][rl] + lsf[1][rl]);
        const int j = jt * 64 + rl;
        const size_t orow = (((size_t)t * ROWS + b * SS + j) << 9) + h * 64;
#pragma unroll
        for (int ct = 0; ct < 2; ++ct)
          Ofin[orow + wc * 32 + ct * 16 + ln] = oacc[ct][r] * rinv;
        lsum[r] = 0.f;
      }
      oacc[0] = (f32x4){0.f, 0.f, 0.f, 0.f};
      oacc[1] = (f32x4){0.f, 0.f, 0.f, 0.f};
      if (jt == jA) LOAD_AQ(jB);
    }
    jt = jt2; kt = kt2;
  }
}

// ============================================================
// ln: y = resid + O (pre-normalized), layernorm. One wave per row.
// ============================================================
__global__ __launch_bounds__(256) void ln_kernel(
    const float* __restrict__ u_emb, const float* __restrict__ f_emb,
    const float* __restrict__ Ofin, float* __restrict__ out) {
  const int rid = blockIdx.x * 4 + (threadIdx.x >> 6);
  const int lane = threadIdx.x & 63;
  const int t = rid >> 11, row = rid & 2047;
  const float* resid = t ? f_emb : u_emb;
  const size_t base = (size_t)row * 512;
  const size_t obase = ((size_t)t * ROWS + row) * 512;
  const int o = lane * 8;

  const float4 n0 = *(const float4*)&Ofin[obase + o];
  const float4 n1 = *(const float4*)&Ofin[obase + o + 4];
  const float4 r0 = *(const float4*)&resid[base + o];
  const float4 r1 = *(const float4*)&resid[base + o + 4];
  float y[8];
  y[0] = r0.x + n0.x; y[1] = r0.y + n0.y;
  y[2] = r0.z + n0.z; y[3] = r0.w + n0.w;
  y[4] = r1.x + n1.x; y[5] = r1.y + n1.y;
  y[6] = r1.z + n1.z; y[7] = r1.w + n1.w;

  float s = 0.f, q = 0.f;
#pragma unroll
  for (int i = 0; i < 8; ++i) {
    s += y[i];
    q += y[i] * y[i];
  }
#pragma unroll
  for (int off = 1; off < 64; off <<= 1) {
    s += __shfl_xor(s, off);
    q += __shfl_xor(q, off);
  }
  const float mean = s * (1.f / 512.f);
  const float var = q * (1.f / 512.f) - mean * mean;
  const float rstd = rsqrtf(var + 1e-5f);

  float4 o0, o1;
  o0.x = (y[0] - mean) * rstd; o0.y = (y[1] - mean) * rstd;
  o0.z = (y[2] - mean) * rstd; o0.w = (y[3] - mean) * rstd;
  o1.x = (y[4] - mean) * rstd; o1.y = (y[5] - mean) * rstd;
  o1.z = (y[6] - mean) * rstd; o1.w = (y[7] - mean) * rstd;
  *(float4*)&out[obase + o] = o0;
  *(float4*)&out[obase + o + 4] = o1;
}

// ============================================================
extern "C" void kernel_launch(void* const* d_in, const int* in_sizes, int n_in,
                              void* d_out, int out_size, void* d_ws,
                              size_t ws_size, hipStream_t stream) {
  (void)in_sizes; (void)n_in; (void)out_size; (void)ws_size;
  const float* u_emb = (const float*)d_in[0];
  const float* f_emb = (const float*)d_in[1];
  const float* gpe = (const float*)d_in[2];
  const float* Wq_w = (const float*)d_in[5];
  const float* Wq_b = (const float*)d_in[6];
  const float* Wkv_w = (const float*)d_in[7];
  const float* Wkv_b = (const float*)d_in[8];
  const float* Wp_w = (const float*)d_in[9];
  const float* Wp_b = (const float*)d_in[10];
  const float* Wu_w = (const float*)d_in[11];
  const float* Wu_b = (const float*)d_in[12];
  const float* Bfc = (const float*)d_in[13];
  const float* Bfp = (const float*)d_in[14];
  const float* Buc = (const float*)d_in[15];
  const float* Bup = (const float*)d_in[16];
  float* out = (float*)d_out;

  ushort_t* ws = (ushort_t*)d_ws;
  const size_t SZ = (size_t)ROWS * EMB;       // 1048576
  ushort_t* Qcomb = ws;                       // 4*SZ
  ushort_t* Kcomb = ws + 4 * SZ;              // 2*SZ
  ushort_t* vhT = ws + 6 * SZ;                // SZ
  float* Ofin = (float*)(ws + 7 * SZ);        // 2M floats (8 MB)
  ushort_t* fembB = ws + 12 * SZ;             // SZ        (2048x512 bf16)
  ushort_t* gpeB = ws + 13 * SZ;              // SZ/4      (2048x128 bf16)
  ushort_t* WuT = ws + 13 * SZ + SZ / 4;      // SZ/4      (512x512 [n][k])
  ushort_t* WqT = ws + 13 * SZ + SZ / 2;      // SZ/4
  ushort_t* WkvT = ws + 13 * SZ + 3 * (SZ / 4);  // SZ/2   (1024x512 [n][k])
  ushort_t* WpT = ws + 13 * SZ + 5 * (SZ / 4);   // SZ/16  (512x128 [n][k])

  dim3 blk(256);
  hipLaunchKernelGGL(prep_kernel, dim3(433), blk, 0, stream, f_emb, gpe, Wu_w,
                     Wq_w, Wkv_w, Wp_w, fembB, gpeB, WuT, WqT, WkvT, WpT,
                     Qcomb);
  hipLaunchKernelGGL(projpe_kernel, dim3(40, 16), blk, 0, stream, fembB, gpeB,
                     WuT, WqT, WkvT, WpT, Wu_b, Wq_b, Wkv_b, Wp_b, Buc, Bup,
                     Bfc, Bfp, Qcomb, Kcomb, vhT);
  hipLaunchKernelGGL(attn_kernel, dim3(256), dim3(512), 0, stream, Qcomb,
                     Kcomb, vhT, Ofin);
  hipLaunchKernelGGL(ln_kernel, dim3(1024), blk, 0, stream, u_emb, f_emb,
                     Ofin, out);
}

// Round 4
// 146.675 us; speedup vs baseline: 1.0865x; 1.0102x over previous
//
#include <hip/hip_runtime.h>
#include <math.h>

#define EMB 512
#define NH 8
#define HD 64
#define BB 2
#define SS 1024
#define ROWS (BB * SS) /* 2048 */

typedef __attribute__((ext_vector_type(8))) short bhalf8;
typedef __attribute__((ext_vector_type(4))) float f32x4;
typedef __attribute__((ext_vector_type(8))) unsigned short us8;
typedef unsigned short ushort_t;

typedef const __attribute__((address_space(1))) void gas_void;
typedef __attribute__((address_space(3))) void las_void;

__device__ __forceinline__ void gl2lds16(const void* g, void* l) {
  __builtin_amdgcn_global_load_lds((gas_void*)g, (las_void*)l, 16, 0, 0);
}

__device__ __forceinline__ unsigned short f2bf(float x) {
  unsigned u = __float_as_uint(x);
  u = (u + 0x7FFFu + ((u >> 16) & 1u)) >> 16;
  return (unsigned short)u;
}
__device__ __forceinline__ float bf2f(unsigned short v) {
  return __uint_as_float(((unsigned)v) << 16);
}
__device__ __forceinline__ float fast_tanh(float x) {
  x = fminf(15.f, fmaxf(-15.f, x));
  const float e = __expf(2.f * x);
  return (e - 1.f) / (e + 1.f);
}

// ============================================================
// prep: one-time f32->bf16 conversion of A-operands (f_emb, gpe),
// bf16 TRANSPOSED weights W^T[n][k], plus Qcomb row-1023 zero.
// ============================================================
__global__ __launch_bounds__(256) void prep_kernel(
    const float* __restrict__ f_emb, const float* __restrict__ gpe,
    const float* __restrict__ Wu, const float* __restrict__ Wq,
    const float* __restrict__ Wkv, const float* __restrict__ Wp,
    ushort_t* __restrict__ fembB, ushort_t* __restrict__ gpeB,
    ushort_t* __restrict__ WuT, ushort_t* __restrict__ WqT,
    ushort_t* __restrict__ WkvT, ushort_t* __restrict__ WpT,
    ushort_t* __restrict__ Qcomb) {
  __shared__ __align__(16) ushort_t sT[64 * 72];
  const int bid = blockIdx.x;
  const int tid = threadIdx.x;

  if (bid < 160) {  // contiguous f32 -> bf16
    const bool isF = bid < 128;
    const float* src = isF ? f_emb : gpe;
    ushort_t* dst = isF ? fembB : gpeB;
    const size_t base = (size_t)(isF ? bid : bid - 128) * 8192;
#pragma unroll
    for (int j = 0; j < 4; ++j) {
      const size_t off = base + ((size_t)j * 256 + tid) * 8;
      const float4 a = *(const float4*)&src[off];
      const float4 b = *(const float4*)&src[off + 4];
      us8 o;
      o[0] = f2bf(a.x); o[1] = f2bf(a.y); o[2] = f2bf(a.z); o[3] = f2bf(a.w);
      o[4] = f2bf(b.x); o[5] = f2bf(b.y); o[6] = f2bf(b.z); o[7] = f2bf(b.w);
      *(us8*)&dst[off] = o;
    }
  } else if (bid < 432) {  // 64x64 transpose tiles, f32 -> bf16
    int t = bid - 160;
    const float* W;
    ushort_t* WT;
    int Nw, Kd, k0, n0;
    if (t < 64) {
      W = Wu; WT = WuT; Nw = 512; Kd = 512;
      k0 = (t >> 3) * 64; n0 = (t & 7) * 64;
    } else if (t < 128) {
      t -= 64; W = Wq; WT = WqT; Nw = 512; Kd = 512;
      k0 = (t >> 3) * 64; n0 = (t & 7) * 64;
    } else if (t < 256) {
      t -= 128; W = Wkv; WT = WkvT; Nw = 1024; Kd = 512;
      k0 = (t >> 4) * 64; n0 = (t & 15) * 64;
    } else {
      t -= 256; W = Wp; WT = WpT; Nw = 512; Kd = 128;
      k0 = (t >> 3) * 64; n0 = (t & 7) * 64;
    }
    const int kk = tid >> 2, seg = tid & 3;
    const float* src = &W[(size_t)(k0 + kk) * Nw + n0 + seg * 16];
    float v[16];
    *(float4*)&v[0] = *(const float4*)&src[0];
    *(float4*)&v[4] = *(const float4*)&src[4];
    *(float4*)&v[8] = *(const float4*)&src[8];
    *(float4*)&v[12] = *(const float4*)&src[12];
#pragma unroll
    for (int i = 0; i < 16; ++i) sT[(seg * 16 + i) * 72 + kk] = f2bf(v[i]);
    __syncthreads();
#pragma unroll
    for (int p = 0; p < 2; ++p) {
      const int idx = p * 256 + tid;
      const int n = idx >> 3, c8 = (idx & 7) * 8;
      const us8 o = *(const us8*)&sT[n * 72 + c8];
      *(us8*)&WT[(size_t)(n0 + n) * Kd + k0 + c8] = o;
    }
  } else {  // Qcomb qp-half of row 1023
    const int t2 = tid >> 7, rem = tid & 127;
    const int h = rem >> 4, d4 = (rem & 15) * 4;
    *(ushort4*)&Qcomb[((size_t)t2 * ROWS + 1023) * 1024 + h * 128 + 64 + d4] =
        make_ushort4(0, 0, 0, 0);
  }
}

// ============================================================
// proj+pe GEMM: m97-style DMA pipeline (unchanged from R2).
// ============================================================
__global__ __launch_bounds__(256, 3) void projpe_kernel(
    const ushort_t* __restrict__ fembB, const ushort_t* __restrict__ gpeB,
    const ushort_t* __restrict__ WuT, const ushort_t* __restrict__ WqT,
    const ushort_t* __restrict__ WkvT, const ushort_t* __restrict__ WpT,
    const float* __restrict__ Wu_b, const float* __restrict__ Wq_b,
    const float* __restrict__ Wkv_b, const float* __restrict__ Wp_b,
    const float* __restrict__ Buc, const float* __restrict__ Bup,
    const float* __restrict__ Bfc, const float* __restrict__ Bfp,
    ushort_t* __restrict__ Qcomb, ushort_t* __restrict__ Kcomb,
    ushort_t* __restrict__ vhT) {
  const int bx = blockIdx.x;
  const int mb = blockIdx.y * 128;
  const int tid = threadIdx.x;
  const int w = tid >> 6, lane = tid & 63;
  const int ln = lane & 15, quad = lane >> 4;
  const int wm = (w >> 1) * 64, wn = (w & 1) * 32;

  __shared__ __align__(16) ushort_t sMem[24576];  // 48 KB

  const bool isPe = (bx >= 32);
  const int nb = isPe ? 0 : bx * 64;
  const int npbase = isPe ? (bx - 32) * 64 : 0;
  const ushort_t* Asrc = isPe ? gpeB : fembB;
  const int lda = isPe ? 128 : 512;
  const int trips = isPe ? 2 : 8;

  const ushort_t* Wt;
  int Kd, coff;
  if (isPe) { Wt = WpT; Kd = 128; coff = npbase; }
  else if (nb < 512) { Wt = WuT; Kd = 512; coff = nb; }
  else if (nb < 1024) { Wt = WqT; Kd = 512; coff = nb - 512; }
  else { Wt = WkvT; Kd = 512; coff = nb - 1024; }

  const int l3 = lane >> 3, c7 = lane & 7;
  const int swz = (c7 ^ l3) * 8;  // pre-swizzled source chunk (linear dest)

#define STAGE_PP(T_, P_)                                                     \
  {                                                                          \
    const int k1_ = (T_) * 64;                                               \
    ushort_t* dA_ = sMem + (P_) * 8192;                                      \
    ushort_t* dB_ = sMem + 16384 + (P_) * 4096;                              \
    _Pragma("unroll") for (int s_ = 0; s_ < 4; ++s_) {                       \
      const int q_ = w * 4 + s_;                                             \
      const int r_ = q_ * 8 + l3;                                            \
      gl2lds16(&Asrc[(size_t)(mb + r_) * lda + k1_ + swz], &dA_[q_ * 512]);  \
    }                                                                        \
    _Pragma("unroll") for (int s_ = 0; s_ < 2; ++s_) {                       \
      const int q_ = w * 2 + s_;                                             \
      const int r_ = q_ * 8 + l3;                                            \
      gl2lds16(&Wt[(size_t)(coff + r_) * Kd + k1_ + swz], &dB_[q_ * 512]);   \
    }                                                                        \
  }

  f32x4 acc[4][2];
#pragma unroll
  for (int rt = 0; rt < 4; ++rt)
#pragma unroll
    for (int ct = 0; ct < 2; ++ct) acc[rt][ct] = (f32x4){0.f, 0.f, 0.f, 0.f};

  STAGE_PP(0, 0);

  for (int t0 = 0; t0 < trips; ++t0) {
    __syncthreads();
    if (t0 < trips - 1) STAGE_PP(t0 + 1, (t0 + 1) & 1);
    const ushort_t* bA = sMem + (t0 & 1) * 8192;
    const ushort_t* bB = sMem + 16384 + (t0 & 1) * 4096;
#pragma unroll
    for (int kc = 0; kc < 2; ++kc) {
      bhalf8 af[4], bfr[2];
#pragma unroll
      for (int rt = 0; rt < 4; ++rt) {
        const int row = wm + rt * 16 + ln;
        af[rt] = *(const bhalf8*)&bA[row * 64 +
                                     (((kc * 4 + quad) ^ (row & 7)) << 3)];
      }
#pragma unroll
      for (int ct = 0; ct < 2; ++ct) {
        const int row = wn + ct * 16 + ln;
        bfr[ct] = *(const bhalf8*)&bB[row * 64 +
                                      (((kc * 4 + quad) ^ (row & 7)) << 3)];
      }
#pragma unroll
      for (int rt = 0; rt < 4; ++rt)
#pragma unroll
        for (int ct = 0; ct < 2; ++ct)
          acc[rt][ct] = __builtin_amdgcn_mfma_f32_16x16x32_bf16(
              af[rt], bfr[ct], acc[rt][ct], 0, 0, 0);
    }
  }

  __syncthreads();
  ushort_t* sOut = sMem;

  if (!isPe && nb >= 1536) {
#pragma unroll
    for (int ct = 0; ct < 2; ++ct) {
      const int nl = wn + ct * 16 + ln;
      const float wb = Wkv_b[nb + nl - 1024];
#pragma unroll
      for (int rt = 0; rt < 4; ++rt)
#pragma unroll
        for (int r = 0; r < 4; ++r) {
          const int ml = wm + rt * 16 + quad * 4 + r;
          sOut[nl * 136 + ml] = f2bf(fast_tanh(acc[rt][ct][r] + wb));
        }
    }
    __syncthreads();
    const int b = mb >> 10, mo = mb & 1023;
#pragma unroll
    for (int i = 0; i < 4; ++i) {
      const int idx = tid + i * 256;
      const int nl = idx >> 4, m8 = (idx & 15) * 8;
      const us8 v = *(const us8*)&sOut[nl * 136 + m8];
      *(us8*)&vhT[((size_t)b * 512 + (nb - 1536) + nl) * 1024 + mo + m8] = v;
    }
  } else {
    const float* WB =
        isPe ? Wp_b : (nb < 512 ? Wu_b : (nb < 1024 ? Wq_b : Wkv_b));
    const int woff =
        isPe ? npbase : (nb < 512 ? nb : (nb < 1024 ? nb - 512 : nb - 1024));
    const bool rawDump = (!isPe && nb < 1024);
#pragma unroll
    for (int ct = 0; ct < 2; ++ct) {
      const int nl = wn + ct * 16 + ln;
      const float wb = WB[woff + nl];
#pragma unroll
      for (int rt = 0; rt < 4; ++rt)
#pragma unroll
        for (int r = 0; r < 4; ++r) {
          const int ml = wm + rt * 16 + quad * 4 + r;
          const float v = acc[rt][ct][r] + wb;
          sOut[ml * 72 + nl] = f2bf(rawDump ? v : fast_tanh(v));
        }
    }
    __syncthreads();
#pragma unroll
    for (int i = 0; i < 4; ++i) {
      const int idx = tid + i * 256;
      const int rr = idx >> 3, c8 = (idx & 7) * 8;
      const int m = mb + rr;
      const us8 v = *(const us8*)&sOut[rr * 72 + c8];
      if (isPe) {
        const int n = npbase + c8;
        const int h = n >> 6;
        *(us8*)&Kcomb[(size_t)m * 1024 + h * 128 + 64 + (n & 63)] = v;
      } else if (nb < 1024) {
        const int strm = nb >= 512 ? 1 : 0;
        const int n = (nb - strm * 512) + c8;
        const int h = n >> 6;
        const float* BC = strm ? Bfc : Buc;
        const float* BP = strm ? Bfp : Bup;
        float bcA[8], bpA[8];
        *(float4*)&bcA[0] = *(const float4*)&BC[n];
        *(float4*)&bcA[4] = *(const float4*)&BC[n + 4];
        *(float4*)&bpA[0] = *(const float4*)&BP[n];
        *(float4*)&bpA[4] = *(const float4*)&BP[n + 4];
        us8 oc, op;
#pragma unroll
        for (int jj = 0; jj < 8; ++jj) {
          const float vv = bf2f((unsigned short)v[jj]);
          oc[jj] = f2bf(fast_tanh(vv + bcA[jj]));
          op[jj] = f2bf(fast_tanh(vv + bpA[jj]));
        }
        *(us8*)&Qcomb[((size_t)strm * ROWS + m) * 1024 + h * 128 + (n & 63)] =
            oc;
        if (m != 0) {
          const int mp = (m < 1024) ? m - 1 : m;
          *(us8*)&Qcomb[((size_t)strm * ROWS + mp) * 1024 + h * 128 + 64 +
                        (n & 63)] = op;
        }
      } else {
        const int n = (nb - 1024) + c8;
        const int h = n >> 6;
        *(us8*)&Kcomb[(size_t)m * 1024 + h * 128 + (n & 63)] = v;
      }
    }
  }
}

// ============================================================
// attn: flash MFMA, static-max softmax, zero atomics, WARP-AUTONOMOUS.
// 512 blocks x 256 thr; block = (combo, jt): owns row-block jt, iterates
// kt=0..jt. Each warp owns 16 rows x ALL 64 cols -> softmax row-sum is
// wave-local (shuffle only), sP is warp-private: NO cross-warp barrier
// mid-iter, ONE __syncthreads per iter (KV DMA drain). Q loaded once.
// 2 blocks/CU for phase-overlap. XCD swizzle: each XCD owns 4 combos
// entirely -> K/V/Q working set 2.5 MB, L2-resident.
// Diag mask: global row = w*16 + quad*4 + r  (w*16 term REQUIRED - R3 bug).
// ============================================================
__global__ __launch_bounds__(256, 2) void attn_kernel(
    const ushort_t* __restrict__ Qcomb, const ushort_t* __restrict__ Kcomb,
    const ushort_t* __restrict__ vhT, float* __restrict__ Ofin) {
  const int pbid = blockIdx.x;
  const int lbid = (pbid & 7) * 64 + (pbid >> 3);  // bijective XCD swizzle
  const int c = lbid >> 4, jt = lbid & 15;
  const int tid = threadIdx.x;
  const int w = tid >> 6, lane = tid & 63;
  const int ln = lane & 15, quad = lane >> 4;
  const int l4 = lane >> 4, p15 = lane & 15;
  const int l3 = lane >> 3, l7 = lane & 7;
  const int t = c >> 4, b = (c >> 3) & 1, h = c & 7;

  __shared__ __align__(16) ushort_t sK[2 * 8192];  // 32 KB
  __shared__ __align__(16) ushort_t sV[2 * 4096];  // 16 KB
  __shared__ __align__(16) ushort_t sP[64 * 72];   // 9 KB (warp-private rows)

#define STAGE_KV(KT_, BUF_)                                                   \
  {                                                                           \
    const size_t kb_ = ((size_t)b * SS + (KT_)*64) * 1024 + h * 128;          \
    ushort_t* bk_ = sK + (BUF_)*8192;                                         \
    _Pragma("unroll") for (int s_ = 0; s_ < 4; ++s_) {                        \
      const int q_ = w * 4 + s_;                                              \
      const int r_ = q_ * 4 + l4;                                             \
      const int gl_ = p15 ^ (r_ & 7);                                         \
      gl2lds16(&Kcomb[kb_ + (size_t)r_ * 1024 + gl_ * 8], &bk_[q_ * 512]);    \
    }                                                                         \
    const size_t vb_ = ((size_t)b * 512 + h * 64) * 1024 + (KT_)*64;          \
    ushort_t* bv_ = sV + (BUF_)*4096;                                         \
    _Pragma("unroll") for (int s_ = 0; s_ < 2; ++s_) {                        \
      const int q_ = w * 2 + s_;                                              \
      const int r_ = q_ * 8 + l3;                                             \
      const int gl_ = l7 ^ (r_ & 7);                                          \
      gl2lds16(&vhT[vb_ + (size_t)r_ * 1024 + gl_ * 8], &bv_[q_ * 512]);      \
    }                                                                         \
  }

  STAGE_KV(0, 0);

  // Q fragments (jt fixed per block -> load once)
  bhalf8 aq[4];
  {
    const size_t qb_ =
        ((size_t)t * ROWS + b * SS + jt * 64 + w * 16 + ln) * 1024 + h * 128 +
        quad * 8;
#pragma unroll
    for (int kc = 0; kc < 4; ++kc)
      aq[kc] = *(const bhalf8*)&Qcomb[qb_ + kc * 32];
  }

  f32x4 oacc[4];
#pragma unroll
  for (int ct = 0; ct < 4; ++ct) oacc[ct] = (f32x4){0.f, 0.f, 0.f, 0.f};
  float lsum[4] = {0.f, 0.f, 0.f, 0.f};

  for (int kt = 0; kt <= jt; ++kt) {
    __syncthreads();  // drains buffer (kt&1)'s DMA; syncs block
    const ushort_t* bK = sK + (kt & 1) * 8192;
    const ushort_t* bV = sV + (kt & 1) * 4096;
    if (kt < jt) STAGE_KV(kt + 1, (kt + 1) & 1);

    // S = Q @ K^T : this warp's 16 rows x 64 cols
    f32x4 sacc[4];
#pragma unroll
    for (int ct = 0; ct < 4; ++ct) {
      sacc[ct] = (f32x4){0.f, 0.f, 0.f, 0.f};
#pragma unroll
      for (int kc = 0; kc < 4; ++kc) {
        const bhalf8 bk = *(const bhalf8*)&bK[(ct * 16 + ln) * 128 +
                                              (((kc * 4 + quad) ^ l7) << 3)];
        sacc[ct] = __builtin_amdgcn_mfma_f32_16x16x32_bf16(aq[kc], bk,
                                                           sacc[ct], 0, 0, 0);
      }
    }

    const bool diag = (kt == jt);
#pragma unroll
    for (int ct = 0; ct < 4; ++ct)
#pragma unroll
      for (int r = 0; r < 4; ++r) {
        float p;
        if (diag && (ct * 16 + ln > w * 16 + quad * 4 + r))
          p = 0.f;
        else
          p = __expf(sacc[ct][r] * 0.125f - 16.f);
        sacc[ct][r] = p;
        lsum[r] += p;
      }

    // P -> LDS (warp-private rows; no cross-warp exchange)
#pragma unroll
    for (int ct = 0; ct < 4; ++ct)
#pragma unroll
      for (int r = 0; r < 4; ++r)
        sP[(w * 16 + quad * 4 + r) * 72 + ct * 16 + ln] =
            (ushort_t)(__float_as_uint(sacc[ct][r]) >> 16);

    // wave-local LDS drain only; K/V DMA prefetch stays in flight
    asm volatile("s_waitcnt lgkmcnt(0)" ::: "memory");
    __builtin_amdgcn_sched_barrier(0);

    // O += P @ V : this warp's 16 rows x 64 d-cols
#pragma unroll
    for (int kc = 0; kc < 2; ++kc) {
      const bhalf8 ap =
          *(const bhalf8*)&sP[(w * 16 + ln) * 72 + kc * 32 + quad * 8];
#pragma unroll
      for (int ct = 0; ct < 4; ++ct) {
        const bhalf8 bv = *(const bhalf8*)&bV[(ct * 16 + ln) * 64 +
                                              (((kc * 4 + quad) ^ l7) << 3)];
        oacc[ct] = __builtin_amdgcn_mfma_f32_16x16x32_bf16(ap, bv, oacc[ct],
                                                           0, 0, 0);
      }
    }
  }

  // flush: wave-local row-sum reduce, normalize, direct store
#pragma unroll
  for (int r = 0; r < 4; ++r) {
    float s = lsum[r];
    s += __shfl_xor(s, 1);
    s += __shfl_xor(s, 2);
    s += __shfl_xor(s, 4);
    s += __shfl_xor(s, 8);
    const float rinv = 1.f / s;
    const int j = jt * 64 + w * 16 + quad * 4 + r;
    const size_t orow = (((size_t)t * ROWS + b * SS + j) << 9) + h * 64;
#pragma unroll
    for (int ct = 0; ct < 4; ++ct)
      Ofin[orow + ct * 16 + ln] = oacc[ct][r] * rinv;
  }
}

// ============================================================
// ln: y = resid + O (pre-normalized), layernorm. One wave per row.
// ============================================================
__global__ __launch_bounds__(256) void ln_kernel(
    const float* __restrict__ u_emb, const float* __restrict__ f_emb,
    const float* __restrict__ Ofin, float* __restrict__ out) {
  const int rid = blockIdx.x * 4 + (threadIdx.x >> 6);
  const int lane = threadIdx.x & 63;
  const int t = rid >> 11, row = rid & 2047;
  const float* resid = t ? f_emb : u_emb;
  const size_t base = (size_t)row * 512;
  const size_t obase = ((size_t)t * ROWS + row) * 512;
  const int o = lane * 8;

  const float4 n0 = *(const float4*)&Ofin[obase + o];
  const float4 n1 = *(const float4*)&Ofin[obase + o + 4];
  const float4 r0 = *(const float4*)&resid[base + o];
  const float4 r1 = *(const float4*)&resid[base + o + 4];
  float y[8];
  y[0] = r0.x + n0.x; y[1] = r0.y + n0.y;
  y[2] = r0.z + n0.z; y[3] = r0.w + n0.w;
  y[4] = r1.x + n1.x; y[5] = r1.y + n1.y;
  y[6] = r1.z + n1.z; y[7] = r1.w + n1.w;

  float s = 0.f, q = 0.f;
#pragma unroll
  for (int i = 0; i < 8; ++i) {
    s += y[i];
    q += y[i] * y[i];
  }
#pragma unroll
  for (int off = 1; off < 64; off <<= 1) {
    s += __shfl_xor(s, off);
    q += __shfl_xor(q, off);
  }
  const float mean = s * (1.f / 512.f);
  const float var = q * (1.f / 512.f) - mean * mean;
  const float rstd = rsqrtf(var + 1e-5f);

  float4 o0, o1;
  o0.x = (y[0] - mean) * rstd; o0.y = (y[1] - mean) * rstd;
  o0.z = (y[2] - mean) * rstd; o0.w = (y[3] - mean) * rstd;
  o1.x = (y[4] - mean) * rstd; o1.y = (y[5] - mean) * rstd;
  o1.z = (y[6] - mean) * rstd; o1.w = (y[7] - mean) * rstd;
  *(float4*)&out[obase + o] = o0;
  *(float4*)&out[obase + o + 4] = o1;
}

// ============================================================
extern "C" void kernel_launch(void* const* d_in, const int* in_sizes, int n_in,
                              void* d_out, int out_size, void* d_ws,
                              size_t ws_size, hipStream_t stream) {
  (void)in_sizes; (void)n_in; (void)out_size; (void)ws_size;
  const float* u_emb = (const float*)d_in[0];
  const float* f_emb = (const float*)d_in[1];
  const float* gpe = (const float*)d_in[2];
  const float* Wq_w = (const float*)d_in[5];
  const float* Wq_b = (const float*)d_in[6];
  const float* Wkv_w = (const float*)d_in[7];
  const float* Wkv_b = (const float*)d_in[8];
  const float* Wp_w = (const float*)d_in[9];
  const float* Wp_b = (const float*)d_in[10];
  const float* Wu_w = (const float*)d_in[11];
  const float* Wu_b = (const float*)d_in[12];
  const float* Bfc = (const float*)d_in[13];
  const float* Bfp = (const float*)d_in[14];
  const float* Buc = (const float*)d_in[15];
  const float* Bup = (const float*)d_in[16];
  float* out = (float*)d_out;

  ushort_t* ws = (ushort_t*)d_ws;
  const size_t SZ = (size_t)ROWS * EMB;       // 1048576
  ushort_t* Qcomb = ws;                       // 4*SZ
  ushort_t* Kcomb = ws + 4 * SZ;              // 2*SZ
  ushort_t* vhT = ws + 6 * SZ;                // SZ
  float* Ofin = (float*)(ws + 7 * SZ);        // 2M floats (8 MB)
  ushort_t* fembB = ws + 12 * SZ;             // SZ        (2048x512 bf16)
  ushort_t* gpeB = ws + 13 * SZ;              // SZ/4      (2048x128 bf16)
  ushort_t* WuT = ws + 13 * SZ + SZ / 4;      // SZ/4      (512x512 [n][k])
  ushort_t* WqT = ws + 13 * SZ + SZ / 2;      // SZ/4
  ushort_t* WkvT = ws + 13 * SZ + 3 * (SZ / 4);  // SZ/2   (1024x512 [n][k])
  ushort_t* WpT = ws + 13 * SZ + 5 * (SZ / 4);   // SZ/16  (512x128 [n][k])

  dim3 blk(256);
  hipLaunchKernelGGL(prep_kernel, dim3(433), blk, 0, stream, f_emb, gpe, Wu_w,
                     Wq_w, Wkv_w, Wp_w, fembB, gpeB, WuT, WqT, WkvT, WpT,
                     Qcomb);
  hipLaunchKernelGGL(projpe_kernel, dim3(40, 16), blk, 0, stream, fembB, gpeB,
                     WuT, WqT, WkvT, WpT, Wu_b, Wq_b, Wkv_b, Wp_b, Buc, Bup,
                     Bfc, Bfp, Qcomb, Kcomb, vhT);
  hipLaunchKernelGGL(attn_kernel, dim3(512), blk, 0, stream, Qcomb, Kcomb,
                     vhT, Ofin);
  hipLaunchKernelGGL(ln_kernel, dim3(1024), blk, 0, stream, u_emb, f_emb,
                     Ofin, out);
}